// Round 1
// baseline (427.659 us; speedup 1.0000x reference)
//
#include <hip/hip_runtime.h>
#include <hip/hip_bf16.h>

typedef __attribute__((ext_vector_type(8))) short bf16x8;
typedef __attribute__((ext_vector_type(4))) float f32x4;

static __device__ inline short f2bf(float f) {
    __hip_bfloat16 h = __float2bfloat16(f);
    return *reinterpret_cast<short*>(&h);
}

// ---------------------------------------------------------------------------
// Setup: block 0 computes base[4][256] = (LN(relu(combined@w1+b1))@w2 + b2
//        + 0.3*emo_b) in exact fp32.  Blocks 1..8 pack emo_w -> bf16 in MFMA
//        B-fragment order: frag (ct,ks), lane l holds col=ct*16+(l&15),
//        k = ks*32 + (l>>4)*8 + j, j=0..7 contiguous.
// ---------------------------------------------------------------------------
__global__ __launch_bounds__(1024) void setup_kernel(
    const float* __restrict__ emb_table,
    const float* __restrict__ pitch_w, const float* __restrict__ pitch_b,
    const float* __restrict__ energy_w, const float* __restrict__ energy_b,
    const float* __restrict__ rate_w, const float* __restrict__ rate_b,
    const float* __restrict__ accent_table, const int* __restrict__ accent_level,
    const float* __restrict__ w1, const float* __restrict__ b1,
    const float* __restrict__ ln_g, const float* __restrict__ ln_b,
    const float* __restrict__ w2, const float* __restrict__ b2,
    const float* __restrict__ emo_w, const float* __restrict__ emo_b,
    float* __restrict__ base_out, unsigned short* __restrict__ wpack)
{
    if (blockIdx.x == 0) {
        __shared__ float comb[4][512];
        __shared__ float hbuf[4][256];
        __shared__ float red[32];
        const int tid = threadIdx.x;   // 0..1023
        const int s = tid >> 8;        // speaker 0..3
        const int n = tid & 255;       // output dim
        const int acc_lvl = accent_level[0];

        // fill combined[s][0..511]: [emb(256) | pitch(64) | energy(64) | rate(64) | accent(64)]
        for (int i = n; i < 512; i += 256) {
            float v;
            if (i < 256) {
                v = emb_table[s * 256 + i];
            } else if (i < 320) {
                float pt = (s == 0) ? 0.6f : (s == 1) ? 0.5f : (s == 2) ? 1.1f : 0.95f;
                v = pt * pitch_w[i - 256] + pitch_b[i - 256];
            } else if (i < 384) {
                float et = (s == 0) ? 0.8f : (s == 1) ? 0.6f : (s == 2) ? 0.85f : 0.7f;
                v = et * energy_w[i - 320] + energy_b[i - 320];
            } else if (i < 448) {
                float rt = (s == 0) ? 1.1f : (s == 1) ? 0.9f : (s == 2) ? 1.15f : 1.0f;
                v = rt * rate_w[i - 384] + rate_b[i - 384];
            } else {
                v = accent_table[acc_lvl * 64 + (i - 448)];
            }
            comb[s][i] = v;
        }
        __syncthreads();

        // h = relu(combined @ w1 + b1)
        float h = b1[n];
        for (int k = 0; k < 512; ++k) h = fmaf(comb[s][k], w1[k * 256 + n], h);
        h = fmaxf(h, 0.0f);

        // LayerNorm over the 256 threads of this speaker group
        float sum = h, sq = h * h;
        for (int m = 32; m; m >>= 1) {
            sum += __shfl_xor(sum, m, 64);
            sq  += __shfl_xor(sq, m, 64);
        }
        const int wave = tid >> 6;   // 0..15
        if ((tid & 63) == 0) { red[wave] = sum; red[16 + wave] = sq; }
        __syncthreads();
        const int w0 = s * 4;
        sum = red[w0] + red[w0 + 1] + red[w0 + 2] + red[w0 + 3];
        sq  = red[16 + w0] + red[16 + w0 + 1] + red[16 + w0 + 2] + red[16 + w0 + 3];
        const float mu  = sum * (1.0f / 256.0f);
        const float var = sq * (1.0f / 256.0f) - mu * mu;
        const float hn = (h - mu) * rsqrtf(var + 1e-5f) * ln_g[n] + ln_b[n];
        hbuf[s][n] = hn;
        __syncthreads();

        // base = hn @ w2 + b2 + 0.3*emo_b
        float o = b2[n] + 0.3f * emo_b[n];
        for (int k = 0; k < 256; ++k) o = fmaf(hbuf[s][k], w2[k * 256 + n], o);
        base_out[s * 256 + n] = o;
    } else {
        // pack emo_w: 8192 fragment-lanes, one 16B store each
        const int idx = (blockIdx.x - 1) * 1024 + threadIdx.x;   // 0..8191
        const int l  = idx & 63;
        const int ks = (idx >> 6) & 7;
        const int ct = idx >> 9;
        const int col = ct * 16 + (l & 15);
        const int kb  = ks * 32 + (l >> 4) * 8;
        bf16x8 pk;
        #pragma unroll
        for (int j = 0; j < 8; ++j) pk[j] = f2bf(emo_w[(kb + j) * 256 + col]);
        *reinterpret_cast<bf16x8*>(wpack + (size_t)idx * 8) = pk;
    }
}

// ---------------------------------------------------------------------------
// Main: out[i] = normalize(base[sid[i]] + 0.3 * (emo[i] @ emo_w))
// Each wave owns 16 complete rows x 256 cols -> norm is wave-local.
// ---------------------------------------------------------------------------
__global__ __launch_bounds__(256) void main_kernel(
    const float* __restrict__ emo, const int* __restrict__ sid,
    const float* __restrict__ base, const unsigned short* __restrict__ wpack,
    float* __restrict__ out)
{
    const int wave = threadIdx.x >> 6;
    const int lane = threadIdx.x & 63;
    const int row0 = blockIdx.x * 64 + wave * 16;
    const int arow = lane & 15;   // A-fragment row within 16-row tile
    const int agrp = lane >> 4;   // k-group

    const float* aptr = emo + (size_t)(row0 + arow) * 256 + agrp * 8;
    const unsigned short* bptr = wpack + (size_t)lane * 8;

    f32x4 acc[16];
    const f32x4 zero = {0.f, 0.f, 0.f, 0.f};
    #pragma unroll
    for (int i = 0; i < 16; ++i) acc[i] = zero;

    #pragma unroll
    for (int ks = 0; ks < 8; ++ks) {
        f32x4 a0 = *reinterpret_cast<const f32x4*>(aptr + ks * 32);
        f32x4 a1 = *reinterpret_cast<const f32x4*>(aptr + ks * 32 + 4);
        bf16x8 af;
        af[0] = f2bf(a0[0]); af[1] = f2bf(a0[1]); af[2] = f2bf(a0[2]); af[3] = f2bf(a0[3]);
        af[4] = f2bf(a1[0]); af[5] = f2bf(a1[1]); af[6] = f2bf(a1[2]); af[7] = f2bf(a1[3]);
        #pragma unroll
        for (int ct = 0; ct < 16; ++ct) {
            bf16x8 bfr = *reinterpret_cast<const bf16x8*>(bptr + ((ct * 8 + ks) << 9));
            acc[ct] = __builtin_amdgcn_mfma_f32_16x16x32_bf16(af, bfr, acc[ct], 0, 0, 0);
        }
    }

    // epilogue: add base, row sum-of-squares, normalize, store
    // C layout: col = ct*16 + (lane&15), row = row0 + (lane>>4)*4 + j
    int sidv[4];
    #pragma unroll
    for (int j = 0; j < 4; ++j) sidv[j] = sid[row0 + agrp * 4 + j];

    float p[4] = {0.f, 0.f, 0.f, 0.f};
    #pragma unroll
    for (int ct = 0; ct < 16; ++ct) {
        #pragma unroll
        for (int j = 0; j < 4; ++j) {
            float pre = fmaf(0.3f, acc[ct][j], base[sidv[j] * 256 + ct * 16 + arow]);
            acc[ct][j] = pre;
            p[j] = fmaf(pre, pre, p[j]);
        }
    }
    #pragma unroll
    for (int j = 0; j < 4; ++j) {
        p[j] += __shfl_xor(p[j], 1, 64);
        p[j] += __shfl_xor(p[j], 2, 64);
        p[j] += __shfl_xor(p[j], 4, 64);
        p[j] += __shfl_xor(p[j], 8, 64);
        float nrm = fmaxf(sqrtf(p[j]), 1e-12f);
        p[j] = 1.0f / nrm;
    }
    #pragma unroll
    for (int ct = 0; ct < 16; ++ct) {
        #pragma unroll
        for (int j = 0; j < 4; ++j) {
            out[(size_t)(row0 + agrp * 4 + j) * 256 + ct * 16 + arow] = acc[ct][j] * p[j];
        }
    }
}

extern "C" void kernel_launch(void* const* d_in, const int* in_sizes, int n_in,
                              void* d_out, int out_size, void* d_ws, size_t ws_size,
                              hipStream_t stream) {
    const int*   sid          = (const int*)d_in[0];
    const float* emo          = (const float*)d_in[1];
    const int*   accent_level = (const int*)d_in[2];
    const float* emb_table    = (const float*)d_in[3];
    const float* pitch_w      = (const float*)d_in[4];
    const float* pitch_b      = (const float*)d_in[5];
    const float* energy_w     = (const float*)d_in[6];
    const float* energy_b     = (const float*)d_in[7];
    const float* rate_w       = (const float*)d_in[8];
    const float* rate_b       = (const float*)d_in[9];
    const float* accent_table = (const float*)d_in[10];
    const float* w1           = (const float*)d_in[11];
    const float* b1           = (const float*)d_in[12];
    const float* ln_g         = (const float*)d_in[13];
    const float* ln_b         = (const float*)d_in[14];
    const float* w2           = (const float*)d_in[15];
    const float* b2           = (const float*)d_in[16];
    const float* emo_w        = (const float*)d_in[17];
    const float* emo_b        = (const float*)d_in[18];

    float* base = (float*)d_ws;                                    // 4*256 fp32 = 4KB
    unsigned short* wpack = (unsigned short*)((char*)d_ws + 4096); // 65536 bf16 = 128KB

    const int B = in_sizes[0];

    setup_kernel<<<9, 1024, 0, stream>>>(emb_table, pitch_w, pitch_b, energy_w, energy_b,
                                         rate_w, rate_b, accent_table, accent_level,
                                         w1, b1, ln_g, ln_b, w2, b2, emo_w, emo_b,
                                         base, wpack);
    main_kernel<<<B / 64, 256, 0, stream>>>(emo, sid, base, wpack, (float*)d_out);
}

// Round 2
// 297.622 us; speedup vs baseline: 1.4369x; 1.4369x over previous
//
#include <hip/hip_runtime.h>
#include <hip/hip_bf16.h>

typedef __attribute__((ext_vector_type(8))) short bf16x8;
typedef __attribute__((ext_vector_type(4))) float f32x4;

static __device__ inline short f2bf(float f) {
    __hip_bfloat16 h = __float2bfloat16(f);
    return *reinterpret_cast<short*>(&h);
}

// ---------------------------------------------------------------------------
// Setup. Blocks 0..3: base[s][256] for speaker s = blockIdx.x, computed with
// 4-way k-split GEMVs (1024 threads: n = t&255, kp = t>>8) + LDS reduction.
// Blocks 4..11: pack emo_w -> bf16 MFMA B-fragment order (frag f=(ct*8+ks):
// lane l holds col=ct*16+(l&15), k = ks*32+(l>>4)*8+j, j=0..7 contiguous).
// ---------------------------------------------------------------------------
__global__ __launch_bounds__(1024) void setup_kernel(
    const float* __restrict__ emb_table,
    const float* __restrict__ pitch_w, const float* __restrict__ pitch_b,
    const float* __restrict__ energy_w, const float* __restrict__ energy_b,
    const float* __restrict__ rate_w, const float* __restrict__ rate_b,
    const float* __restrict__ accent_table, const int* __restrict__ accent_level,
    const float* __restrict__ w1, const float* __restrict__ b1,
    const float* __restrict__ ln_g, const float* __restrict__ ln_b,
    const float* __restrict__ w2, const float* __restrict__ b2,
    const float* __restrict__ emo_w, const float* __restrict__ emo_b,
    float* __restrict__ base_out, unsigned short* __restrict__ wpack)
{
    if (blockIdx.x < 4) {
        const int s = blockIdx.x;
        __shared__ float comb[512];
        __shared__ float part[4][256];
        __shared__ float redS[16];
        __shared__ float redQ[16];
        __shared__ float hbuf[256];
        const int t = threadIdx.x;
        const int n = t & 255;
        const int kp = t >> 8;

        if (t < 512) {
            const int i = t;
            float v;
            if (i < 256) {
                v = emb_table[s * 256 + i];
            } else if (i < 320) {
                float pt = (s == 0) ? 0.6f : (s == 1) ? 0.5f : (s == 2) ? 1.1f : 0.95f;
                v = pt * pitch_w[i - 256] + pitch_b[i - 256];
            } else if (i < 384) {
                float et = (s == 0) ? 0.8f : (s == 1) ? 0.6f : (s == 2) ? 0.85f : 0.7f;
                v = et * energy_w[i - 320] + energy_b[i - 320];
            } else if (i < 448) {
                float rt = (s == 0) ? 1.1f : (s == 1) ? 0.9f : (s == 2) ? 1.15f : 1.0f;
                v = rt * rate_w[i - 384] + rate_b[i - 384];
            } else {
                v = accent_table[accent_level[0] * 64 + (i - 448)];
            }
            comb[i] = v;
        }
        __syncthreads();

        // GEMV1 partial: k in [kp*128, kp*128+128)
        float hp = 0.f;
        {
            const int k0 = kp * 128;
            #pragma unroll 8
            for (int k = 0; k < 128; ++k)
                hp = fmaf(comb[k0 + k], w1[(size_t)(k0 + k) * 256 + n], hp);
        }
        part[kp][n] = hp;
        __syncthreads();

        // every thread (all 4 kp copies) computes identical h for its n
        float h = b1[n] + part[0][n] + part[1][n] + part[2][n] + part[3][n];
        h = fmaxf(h, 0.f);

        // LayerNorm stats: waves 0..3 cover n=0..255 exactly once
        float sum = h, sq = h * h;
        for (int m = 32; m; m >>= 1) {
            sum += __shfl_xor(sum, m, 64);
            sq  += __shfl_xor(sq, m, 64);
        }
        if ((t & 63) == 0) { redS[t >> 6] = sum; redQ[t >> 6] = sq; }
        __syncthreads();
        const float tot = redS[0] + redS[1] + redS[2] + redS[3];
        const float tsq = redQ[0] + redQ[1] + redQ[2] + redQ[3];
        const float mu  = tot * (1.0f / 256.0f);
        const float var = tsq * (1.0f / 256.0f) - mu * mu;
        const float hn = (h - mu) * rsqrtf(var + 1e-5f) * ln_g[n] + ln_b[n];
        if (t < 256) hbuf[n] = hn;
        __syncthreads();

        // GEMV2 partial: k in [kp*64, kp*64+64)
        float op = 0.f;
        {
            const int k0 = kp * 64;
            #pragma unroll 8
            for (int k = 0; k < 64; ++k)
                op = fmaf(hbuf[k0 + k], w2[(size_t)(k0 + k) * 256 + n], op);
        }
        part[kp][n] = op;
        __syncthreads();
        if (t < 256) {
            base_out[s * 256 + n] = b2[n] + 0.3f * emo_b[n]
                                  + part[0][n] + part[1][n] + part[2][n] + part[3][n];
        }
    } else {
        // pack emo_w: 8192 fragment-lanes, one 16B store each
        const int idx = (blockIdx.x - 4) * 1024 + threadIdx.x;   // 0..8191
        const int l  = idx & 63;
        const int ks = (idx >> 6) & 7;
        const int ct = idx >> 9;
        const int col = ct * 16 + (l & 15);
        const int kb  = ks * 32 + (l >> 4) * 8;
        bf16x8 pk;
        #pragma unroll
        for (int j = 0; j < 8; ++j) pk[j] = f2bf(emo_w[(size_t)(kb + j) * 256 + col]);
        *reinterpret_cast<bf16x8*>(wpack + (size_t)idx * 8) = pk;
    }
}

// ---------------------------------------------------------------------------
// Main: out[i] = normalize(base[sid[i]] + 0.3 * (emo[i] @ emo_w))
// 1024-thread block (16 waves), 256 rows/block. B fragments staged in 128KB
// LDS once per block -> all B reads are conflict-free ds_read_b128 with
// compiler-scheduled lgkmcnt. Each wave owns 16 complete rows -> norm is
// wave-local (shuffle only, no barriers after the stage).
// ---------------------------------------------------------------------------
__global__ __launch_bounds__(1024) void main_kernel(
    const float* __restrict__ emo, const int* __restrict__ sid,
    const float* __restrict__ base, const unsigned short* __restrict__ wpack,
    float* __restrict__ out)
{
    extern __shared__ unsigned short sB[];   // 65536 bf16 = 128KB
    const int tid = threadIdx.x;

    // stage packed B into LDS: 8 x 16B per thread, linear
    #pragma unroll
    for (int p = 0; p < 8; ++p) {
        const int e = p * 1024 + tid;        // 16B-unit index 0..8191
        *reinterpret_cast<bf16x8*>(sB + e * 8) =
            *reinterpret_cast<const bf16x8*>(wpack + (size_t)e * 8);
    }
    __syncthreads();

    const int wave = tid >> 6;
    const int lane = tid & 63;
    const int row0 = blockIdx.x * 256 + wave * 16;
    const int arow = lane & 15;   // A-fragment row within 16-row tile
    const int agrp = lane >> 4;   // k-group

    const float* aptr = emo + (size_t)(row0 + arow) * 256 + agrp * 8;
    const unsigned short* bptr = sB + lane * 8;

    f32x4 acc[16];
    const f32x4 zero = {0.f, 0.f, 0.f, 0.f};
    #pragma unroll
    for (int i = 0; i < 16; ++i) acc[i] = zero;

    #pragma unroll
    for (int ks = 0; ks < 8; ++ks) {
        f32x4 a0 = *reinterpret_cast<const f32x4*>(aptr + ks * 32);
        f32x4 a1 = *reinterpret_cast<const f32x4*>(aptr + ks * 32 + 4);
        bf16x8 af;
        af[0] = f2bf(a0[0]); af[1] = f2bf(a0[1]); af[2] = f2bf(a0[2]); af[3] = f2bf(a0[3]);
        af[4] = f2bf(a1[0]); af[5] = f2bf(a1[1]); af[6] = f2bf(a1[2]); af[7] = f2bf(a1[3]);
        #pragma unroll
        for (int ct = 0; ct < 16; ++ct) {
            bf16x8 bfr = *reinterpret_cast<const bf16x8*>(bptr + ((ct * 8 + ks) << 9));
            acc[ct] = __builtin_amdgcn_mfma_f32_16x16x32_bf16(af, bfr, acc[ct], 0, 0, 0);
        }
    }

    // epilogue: add base, row sum-of-squares, normalize, store
    // C layout: col = ct*16 + (lane&15), row = row0 + (lane>>4)*4 + j
    int sidv[4];
    #pragma unroll
    for (int j = 0; j < 4; ++j) sidv[j] = sid[row0 + agrp * 4 + j];

    float p[4] = {0.f, 0.f, 0.f, 0.f};
    #pragma unroll
    for (int ct = 0; ct < 16; ++ct) {
        #pragma unroll
        for (int j = 0; j < 4; ++j) {
            float pre = fmaf(0.3f, acc[ct][j], base[sidv[j] * 256 + ct * 16 + arow]);
            acc[ct][j] = pre;
            p[j] = fmaf(pre, pre, p[j]);
        }
    }
    #pragma unroll
    for (int j = 0; j < 4; ++j) {
        p[j] += __shfl_xor(p[j], 1, 64);
        p[j] += __shfl_xor(p[j], 2, 64);
        p[j] += __shfl_xor(p[j], 4, 64);
        p[j] += __shfl_xor(p[j], 8, 64);
        float nrm = fmaxf(sqrtf(p[j]), 1e-12f);
        p[j] = 1.0f / nrm;
    }
    #pragma unroll
    for (int ct = 0; ct < 16; ++ct) {
        #pragma unroll
        for (int j = 0; j < 4; ++j) {
            out[(size_t)(row0 + agrp * 4 + j) * 256 + ct * 16 + arow] = acc[ct][j] * p[j];
        }
    }
}

extern "C" void kernel_launch(void* const* d_in, const int* in_sizes, int n_in,
                              void* d_out, int out_size, void* d_ws, size_t ws_size,
                              hipStream_t stream) {
    const int*   sid          = (const int*)d_in[0];
    const float* emo          = (const float*)d_in[1];
    const int*   accent_level = (const int*)d_in[2];
    const float* emb_table    = (const float*)d_in[3];
    const float* pitch_w      = (const float*)d_in[4];
    const float* pitch_b      = (const float*)d_in[5];
    const float* energy_w     = (const float*)d_in[6];
    const float* energy_b     = (const float*)d_in[7];
    const float* rate_w       = (const float*)d_in[8];
    const float* rate_b       = (const float*)d_in[9];
    const float* accent_table = (const float*)d_in[10];
    const float* w1           = (const float*)d_in[11];
    const float* b1           = (const float*)d_in[12];
    const float* ln_g         = (const float*)d_in[13];
    const float* ln_b         = (const float*)d_in[14];
    const float* w2           = (const float*)d_in[15];
    const float* b2           = (const float*)d_in[16];
    const float* emo_w        = (const float*)d_in[17];
    const float* emo_b        = (const float*)d_in[18];

    float* base = (float*)d_ws;                                    // 4*256 fp32 = 4KB
    unsigned short* wpack = (unsigned short*)((char*)d_ws + 4096); // 65536 bf16 = 128KB

    const int B = in_sizes[0];

    setup_kernel<<<12, 1024, 0, stream>>>(emb_table, pitch_w, pitch_b, energy_w, energy_b,
                                          rate_w, rate_b, accent_table, accent_level,
                                          w1, b1, ln_g, ln_b, w2, b2, emo_w, emo_b,
                                          base, wpack);
    main_kernel<<<B / 256, 1024, 131072, stream>>>(emo, sid, base, wpack, (float*)d_out);
}